// Round 4
// baseline (337.550 us; speedup 1.0000x reference)
//
#include <hip/hip_runtime.h>
#include <hip/hip_bf16.h>

// TT-linear: out(8192x4096) = x @ W, W from TT cores g1,g2.
// (1) prep: cvt x->bf16 + build W^T bf16. (2) GEMM: 256x256 tile, BK=32,
//     4-buffer LDS (128KB), ONE barrier/phase, 32x32x16 MFMA, vmcnt(8) deep pipeline.

#define TOKENS 8192
#define KDIM 4096
#define NDIM 4096

typedef __attribute__((ext_vector_type(8))) __bf16 bf16x8;
typedef __attribute__((ext_vector_type(16))) float f32x16;
typedef __attribute__((ext_vector_type(8))) unsigned short u16x8;

typedef __attribute__((address_space(1))) unsigned int as1_uint;
typedef __attribute__((address_space(3))) unsigned int as3_uint;

#define GLOAD_LDS16(gp, lp) \
  __builtin_amdgcn_global_load_lds((as1_uint*)(void*)(gp), (as3_uint*)(void*)(lp), 16, 0, 0)

#define BAR() asm volatile("s_barrier" ::: "memory")
#define LGKM0() asm volatile("s_waitcnt lgkmcnt(0)" ::: "memory")
#define VMCNT8() asm volatile("s_waitcnt vmcnt(8)" ::: "memory")

__device__ inline unsigned short f2bf(float f) {
  __hip_bfloat16 h = __float2bfloat16(f);
  return __builtin_bit_cast(unsigned short, h);
}

// ---------------- Kernel 1: merged prep (cvt x -> bf16 ; build Wt[n][k] bf16) ----------------
__global__ __launch_bounds__(256) void prep_kernel(const float* __restrict__ x,
                                                   const float* __restrict__ g1,
                                                   const float* __restrict__ g2,
                                                   unsigned short* __restrict__ xb,
                                                   unsigned short* __restrict__ wt) {
  __shared__ float a_s[64 * 16];  // [m1][r] for fixed n1
  __shared__ float b_s[16 * 64];  // [r][m2] for fixed n2
  const int bid = blockIdx.x;
  const int t = threadIdx.x;

  if (bid < 16384) {
    size_t i = (size_t)bid * 256 + t;
    const float4* p = reinterpret_cast<const float4*>(x) + i * 2;
    float4 v0 = p[0];
    float4 v1 = p[1];
    u16x8 u;
    u[0] = f2bf(v0.x); u[1] = f2bf(v0.y); u[2] = f2bf(v0.z); u[3] = f2bf(v0.w);
    u[4] = f2bf(v1.x); u[5] = f2bf(v1.y); u[6] = f2bf(v1.z); u[7] = f2bf(v1.w);
    reinterpret_cast<u16x8*>(xb)[i] = u;
    return;
  }

  const int n = bid - 16384;
  const int n1 = n >> 6, n2 = n & 63;
  for (int e = t; e < 1024; e += 256) {
    int m1 = e >> 4, r = e & 15;
    a_s[e] = g1[m1 * 1024 + n1 * 16 + r];
  }
  for (int e = t; e < 1024; e += 256) {
    int r = e >> 6, m2 = e & 63;
    b_s[e] = g2[r * 4096 + m2 * 64 + n2];
  }
  __syncthreads();

  unsigned short loc[16];
  const int kbase = t * 16;
#pragma unroll
  for (int kk = 0; kk < 16; ++kk) {
    int k = kbase + kk;
    int m1 = k >> 6, m2 = k & 63;
    float acc = 0.f;
#pragma unroll
    for (int r = 0; r < 16; ++r) acc += a_s[m1 * 16 + r] * b_s[r * 64 + m2];
    loc[kk] = f2bf(acc);
  }
  u16x8* dst = reinterpret_cast<u16x8*>(wt + (size_t)n * KDIM + kbase);
  dst[0] = *reinterpret_cast<u16x8*>(&loc[0]);
  dst[1] = *reinterpret_cast<u16x8*>(&loc[8]);
}

// ---------------- Kernel 2: GEMM 256x256, BK=32, 4-buf, 1 barrier/phase, 32x32x16 ----------------
// out[m][n] = sum_k Xb[m][k] * Wt[n][k].
// LDS buffer c (0..3) at c*32768: A tile [256 rows][32 k]bf16 at +0, B tile at +16384.
// Row = 64B = 4 chunks of 16B; swizzle chunk' = chunk ^ (row&3).
// Phase s: read tile s (buf s&3), stage tile (s+3)&127 (buf (s+3)&3), vmcnt(8)
// [drains tile s+1, issued 2 phases ago], lgkm0, 16 MFMA, barrier.
__global__ __launch_bounds__(512, 2) void gemm_kernel(const unsigned short* __restrict__ Xb,
                                                      const unsigned short* __restrict__ Wt,
                                                      float* __restrict__ out) {
  __shared__ __align__(16) char lds[131072];

  const int t = threadIdx.x;
  const int lane = t & 63;
  const int wave = t >> 6;   // 0..7
  const int wm = wave >> 2;  // 0..1 : 128 output rows
  const int wn = wave & 3;   // 0..3 : 64 output cols

  // 8x8-per-XCD chunking: XCD (bid&7) owns an 8bm x 8bn region of the 32x16 grid
  const int bid = blockIdx.x;
  const int xcd = bid & 7, jj = bid >> 3;
  const int bm = ((xcd >> 1) << 3) + (jj >> 3);
  const int bn = ((xcd & 1) << 3) + (jj & 7);
  const int m0 = bm << 8, n0 = bn << 8;

  // staging: thread t -> half-row t>>2 (within 128-row half), lds chunk t&3,
  // inverse-swizzled global chunk (t&3)^((t>>2)&3).
  const int srow = t >> 2;
  const int csrc = (t & 3) ^ ((t >> 2) & 3);
  const unsigned short* aS = Xb + (size_t)(m0 + srow) * KDIM + csrc * 8;
  const unsigned short* bS = Wt + (size_t)(n0 + srow) * KDIM + csrc * 8;
  const int ldsW = wave << 10;  // wave-uniform 1KB slot

#define STG(kt, bufB) do { \
    const unsigned short* _a = aS + (size_t)(kt) * 32; \
    const unsigned short* _b = bS + (size_t)(kt) * 32; \
    GLOAD_LDS16(_a, lds + (bufB) + ldsW); \
    GLOAD_LDS16(_a + (size_t)128 * KDIM, lds + (bufB) + 8192 + ldsW); \
    GLOAD_LDS16(_b, lds + (bufB) + 16384 + ldsW); \
    GLOAD_LDS16(_b + (size_t)128 * KDIM, lds + (bufB) + 24576 + ldsW); \
  } while (0)

  // fragment reads (32x32x16): lane holds row (lane&31), k = (lane>>5)*8 + e.
  // chunk = kk*2 + (lane>>5); swizzled byte off = ((chunk ^ (lane&3)) << 4).
  // kk=1 differs by chunk XOR 2 -> byte XOR 0x20.
  const int cO = (((lane >> 5) ^ (lane & 3)) << 4);
  const int aRd = (wm * 128 + (lane & 31)) * 64 + cO;           // + i*2048 (+bufB)
  const int bRd = 16384 + (wn * 64 + (lane & 31)) * 64 + cO;    // + j*2048 (+bufB)

#define RD(off) (*(const bf16x8*)(lds + rb + (off)))
#define MF(i, j, A, B) acc[i][j] = __builtin_amdgcn_mfma_f32_32x32x16_bf16((A), (B), acc[i][j], 0, 0, 0)

  f32x16 acc[4][2];
#pragma unroll
  for (int i = 0; i < 4; ++i)
#pragma unroll
    for (int j = 0; j < 2; ++j)
#pragma unroll
      for (int e = 0; e < 16; ++e) acc[i][j][e] = 0.f;

  // ---- prologue: stage tiles 0,1,2 ; tile0 landed (vmcnt 12->8) ----
  STG(0, 0); STG(1, 32768); STG(2, 65536);
  VMCNT8();
  BAR();

#pragma unroll 1
  for (int s = 0; s < 128; ++s) {
    const int rb = (s & 3) << 15;
    const int sb = ((s + 3) & 3) << 15;

    // reads of tile s (12 x ds_read_b128)
    bf16x8 a0k0 = RD(aRd);           bf16x8 a1k0 = RD(aRd + 2048);
    bf16x8 a2k0 = RD(aRd + 4096);    bf16x8 a3k0 = RD(aRd + 6144);
    bf16x8 a0k1 = RD(aRd ^ 32);      bf16x8 a1k1 = RD((aRd + 2048) ^ 32);
    bf16x8 a2k1 = RD((aRd + 4096) ^ 32); bf16x8 a3k1 = RD((aRd + 6144) ^ 32);
    bf16x8 b0k0 = RD(bRd);           bf16x8 b1k0 = RD(bRd + 2048);
    bf16x8 b0k1 = RD(bRd ^ 32);      bf16x8 b1k1 = RD((bRd + 2048) ^ 32);

    // stage tile s+3 (wraps to dummy re-stage of tiles 0-2 at the tail; never read)
    STG((s + 3) & 127, sb);

    VMCNT8();  // tile s+1 fully landed (its 4 loads were issued 2 phases ago)
    LGKM0();   // my 12 reads complete -> values in regs before this phase's barrier

    __builtin_amdgcn_s_setprio(1);
    MF(0, 0, a0k0, b0k0); MF(0, 1, a0k0, b1k0);
    MF(1, 0, a1k0, b0k0); MF(1, 1, a1k0, b1k0);
    MF(2, 0, a2k0, b0k0); MF(2, 1, a2k0, b1k0);
    MF(3, 0, a3k0, b0k0); MF(3, 1, a3k0, b1k0);
    MF(0, 0, a0k1, b0k1); MF(0, 1, a0k1, b1k1);
    MF(1, 0, a1k1, b0k1); MF(1, 1, a1k1, b1k1);
    MF(2, 0, a2k1, b0k1); MF(2, 1, a2k1, b1k1);
    MF(3, 0, a3k1, b0k1); MF(3, 1, a3k1, b1k1);
    __builtin_amdgcn_s_setprio(0);

    BAR();  // single barrier/phase: all waves' reads done (LGKM0 above), vmcnt drained
  }

  // ---- epilogue: 32x32 C/D layout: col = lane&31, row = (reg&3) + 8*(reg>>2) + 4*(lane>>5) ----
  const int ccol = lane & 31;
  const int r0 = (lane >> 5) << 2;
#pragma unroll
  for (int i = 0; i < 4; ++i) {
#pragma unroll
    for (int j = 0; j < 2; ++j) {
      size_t base = (size_t)(m0 + wm * 128 + i * 32 + r0) * NDIM + (n0 + wn * 64 + j * 32 + ccol);
#pragma unroll
      for (int reg = 0; reg < 16; ++reg) {
        int row = (reg & 3) + ((reg >> 2) << 3);
        out[base + (size_t)row * NDIM] = acc[i][j][reg];
      }
    }
  }
}

extern "C" void kernel_launch(void* const* d_in, const int* in_sizes, int n_in,
                              void* d_out, int out_size, void* d_ws, size_t ws_size,
                              hipStream_t stream) {
  const float* x = (const float*)d_in[0];
  const float* g1 = (const float*)d_in[1];
  const float* g2 = (const float*)d_in[2];
  float* out = (float*)d_out;

  unsigned short* Wt = (unsigned short*)d_ws;
  unsigned short* Xb = (unsigned short*)d_ws + (size_t)KDIM * NDIM;

  prep_kernel<<<16384 + NDIM, 256, 0, stream>>>(x, g1, g2, Xb, Wt);
  gemm_kernel<<<(TOKENS / 256) * (NDIM / 256), 512, 0, stream>>>(Xb, Wt, out);
}

// Round 5
// 310.213 us; speedup vs baseline: 1.0881x; 1.0881x over previous
//
#include <hip/hip_runtime.h>
#include <hip/hip_bf16.h>

// TT-linear: out(8192x4096) = x @ W, W from TT cores g1,g2.
// (1) prep: cvt x->bf16 + build W^T bf16. (2) GEMM: 256x256 tile, BK=32,
//     4-buffer LDS (128KB), ONE barrier/phase, 32x32x16 MFMA, vmcnt(8) deep pipeline.
// R4->R5: fixed LDS swizzle g(row) = (row>>1)&3 (was row&3: 4-way bank conflict,
//         7.55e7 conflict cycles). Staging csrc and fragment cO changed; rest identical.

#define TOKENS 8192
#define KDIM 4096
#define NDIM 4096

typedef __attribute__((ext_vector_type(8))) __bf16 bf16x8;
typedef __attribute__((ext_vector_type(16))) float f32x16;
typedef __attribute__((ext_vector_type(8))) unsigned short u16x8;

typedef __attribute__((address_space(1))) unsigned int as1_uint;
typedef __attribute__((address_space(3))) unsigned int as3_uint;

#define GLOAD_LDS16(gp, lp) \
  __builtin_amdgcn_global_load_lds((as1_uint*)(void*)(gp), (as3_uint*)(void*)(lp), 16, 0, 0)

#define BAR() asm volatile("s_barrier" ::: "memory")
#define LGKM0() asm volatile("s_waitcnt lgkmcnt(0)" ::: "memory")
#define VMCNT8() asm volatile("s_waitcnt vmcnt(8)" ::: "memory")

__device__ inline unsigned short f2bf(float f) {
  __hip_bfloat16 h = __float2bfloat16(f);
  return __builtin_bit_cast(unsigned short, h);
}

// ---------------- Kernel 1: merged prep (cvt x -> bf16 ; build Wt[n][k] bf16) ----------------
__global__ __launch_bounds__(256) void prep_kernel(const float* __restrict__ x,
                                                   const float* __restrict__ g1,
                                                   const float* __restrict__ g2,
                                                   unsigned short* __restrict__ xb,
                                                   unsigned short* __restrict__ wt) {
  __shared__ float a_s[64 * 16];  // [m1][r] for fixed n1
  __shared__ float b_s[16 * 64];  // [r][m2] for fixed n2
  const int bid = blockIdx.x;
  const int t = threadIdx.x;

  if (bid < 16384) {
    size_t i = (size_t)bid * 256 + t;
    const float4* p = reinterpret_cast<const float4*>(x) + i * 2;
    float4 v0 = p[0];
    float4 v1 = p[1];
    u16x8 u;
    u[0] = f2bf(v0.x); u[1] = f2bf(v0.y); u[2] = f2bf(v0.z); u[3] = f2bf(v0.w);
    u[4] = f2bf(v1.x); u[5] = f2bf(v1.y); u[6] = f2bf(v1.z); u[7] = f2bf(v1.w);
    reinterpret_cast<u16x8*>(xb)[i] = u;
    return;
  }

  const int n = bid - 16384;
  const int n1 = n >> 6, n2 = n & 63;
  for (int e = t; e < 1024; e += 256) {
    int m1 = e >> 4, r = e & 15;
    a_s[e] = g1[m1 * 1024 + n1 * 16 + r];
  }
  for (int e = t; e < 1024; e += 256) {
    int r = e >> 6, m2 = e & 63;
    b_s[e] = g2[r * 4096 + m2 * 64 + n2];
  }
  __syncthreads();

  unsigned short loc[16];
  const int kbase = t * 16;
#pragma unroll
  for (int kk = 0; kk < 16; ++kk) {
    int k = kbase + kk;
    int m1 = k >> 6, m2 = k & 63;
    float acc = 0.f;
#pragma unroll
    for (int r = 0; r < 16; ++r) acc += a_s[m1 * 16 + r] * b_s[r * 64 + m2];
    loc[kk] = f2bf(acc);
  }
  u16x8* dst = reinterpret_cast<u16x8*>(wt + (size_t)n * KDIM + kbase);
  dst[0] = *reinterpret_cast<u16x8*>(&loc[0]);
  dst[1] = *reinterpret_cast<u16x8*>(&loc[8]);
}

// ---------------- Kernel 2: GEMM 256x256, BK=32, 4-buf, 1 barrier/phase, 32x32x16 ----------------
// out[m][n] = sum_k Xb[m][k] * Wt[n][k].
// LDS buffer c (0..3) at c*32768: A tile [256 rows][32 k]bf16 at +0, B tile at +16384.
// Row = 64B = 4 chunks of 16B; swizzle chunk' = chunk ^ ((row>>1)&3)  [2-way = free].
// Phase s: read tile s (buf s&3), stage tile (s+3)&127 (buf (s+3)&3), vmcnt(8)
// [drains tile s+1, issued 2 phases ago], lgkm0, 16 MFMA, barrier.
__global__ __launch_bounds__(512, 2) void gemm_kernel(const unsigned short* __restrict__ Xb,
                                                      const unsigned short* __restrict__ Wt,
                                                      float* __restrict__ out) {
  __shared__ __align__(16) char lds[131072];

  const int t = threadIdx.x;
  const int lane = t & 63;
  const int wave = t >> 6;   // 0..7
  const int wm = wave >> 2;  // 0..1 : 128 output rows
  const int wn = wave & 3;   // 0..3 : 64 output cols

  // 8x8-per-XCD chunking: XCD (bid&7) owns an 8bm x 8bn region of the 32x16 grid
  const int bid = blockIdx.x;
  const int xcd = bid & 7, jj = bid >> 3;
  const int bm = ((xcd >> 1) << 3) + (jj >> 3);
  const int bn = ((xcd & 1) << 3) + (jj & 7);
  const int m0 = bm << 8, n0 = bn << 8;

  // staging: thread t -> half-row t>>2 (within 128-row half), lds chunk t&3,
  // inverse-swizzled global chunk (t&3)^((t>>3)&3)   [g(row)=(row>>1)&3, row=t>>2].
  const int srow = t >> 2;
  const int csrc = (t & 3) ^ ((t >> 3) & 3);
  const unsigned short* aS = Xb + (size_t)(m0 + srow) * KDIM + csrc * 8;
  const unsigned short* bS = Wt + (size_t)(n0 + srow) * KDIM + csrc * 8;
  const int ldsW = wave << 10;  // wave-uniform 1KB slot

#define STG(kt, bufB) do { \
    const unsigned short* _a = aS + (size_t)(kt) * 32; \
    const unsigned short* _b = bS + (size_t)(kt) * 32; \
    GLOAD_LDS16(_a, lds + (bufB) + ldsW); \
    GLOAD_LDS16(_a + (size_t)128 * KDIM, lds + (bufB) + 8192 + ldsW); \
    GLOAD_LDS16(_b, lds + (bufB) + 16384 + ldsW); \
    GLOAD_LDS16(_b + (size_t)128 * KDIM, lds + (bufB) + 24576 + ldsW); \
  } while (0)

  // fragment reads (32x32x16): lane holds row (lane&31), k = (lane>>5)*8 + e.
  // chunk = kk*2 + (lane>>5); swizzled byte off = ((chunk ^ ((row>>1)&3)) << 4),
  // (row>>1)&3 = (lane>>1)&3 (bases are multiples of 32). kk=1: chunk XOR 2 -> byte XOR 0x20.
  const int cO = (((lane >> 5) ^ ((lane >> 1) & 3)) << 4);
  const int aRd = (wm * 128 + (lane & 31)) * 64 + cO;           // + i*2048 (+bufB)
  const int bRd = 16384 + (wn * 64 + (lane & 31)) * 64 + cO;    // + j*2048 (+bufB)

#define RD(off) (*(const bf16x8*)(lds + rb + (off)))
#define MF(i, j, A, B) acc[i][j] = __builtin_amdgcn_mfma_f32_32x32x16_bf16((A), (B), acc[i][j], 0, 0, 0)

  f32x16 acc[4][2];
#pragma unroll
  for (int i = 0; i < 4; ++i)
#pragma unroll
    for (int j = 0; j < 2; ++j)
#pragma unroll
      for (int e = 0; e < 16; ++e) acc[i][j][e] = 0.f;

  // ---- prologue: stage tiles 0,1,2 ; tile0 landed (vmcnt 12->8) ----
  STG(0, 0); STG(1, 32768); STG(2, 65536);
  VMCNT8();
  BAR();

#pragma unroll 1
  for (int s = 0; s < 128; ++s) {
    const int rb = (s & 3) << 15;
    const int sb = ((s + 3) & 3) << 15;

    // reads of tile s (12 x ds_read_b128)
    bf16x8 a0k0 = RD(aRd);           bf16x8 a1k0 = RD(aRd + 2048);
    bf16x8 a2k0 = RD(aRd + 4096);    bf16x8 a3k0 = RD(aRd + 6144);
    bf16x8 a0k1 = RD(aRd ^ 32);      bf16x8 a1k1 = RD((aRd + 2048) ^ 32);
    bf16x8 a2k1 = RD((aRd + 4096) ^ 32); bf16x8 a3k1 = RD((aRd + 6144) ^ 32);
    bf16x8 b0k0 = RD(bRd);           bf16x8 b1k0 = RD(bRd + 2048);
    bf16x8 b0k1 = RD(bRd ^ 32);      bf16x8 b1k1 = RD((bRd + 2048) ^ 32);

    // stage tile s+3 (wraps to dummy re-stage of tiles 0-2 at the tail; never read)
    STG((s + 3) & 127, sb);

    VMCNT8();  // tile s+1 fully landed (its 4 loads were issued 2 phases ago)
    LGKM0();   // my 12 reads complete -> values in regs before this phase's barrier

    __builtin_amdgcn_s_setprio(1);
    MF(0, 0, a0k0, b0k0); MF(0, 1, a0k0, b1k0);
    MF(1, 0, a1k0, b0k0); MF(1, 1, a1k0, b1k0);
    MF(2, 0, a2k0, b0k0); MF(2, 1, a2k0, b1k0);
    MF(3, 0, a3k0, b0k0); MF(3, 1, a3k0, b1k0);
    MF(0, 0, a0k1, b0k1); MF(0, 1, a0k1, b1k1);
    MF(1, 0, a1k1, b0k1); MF(1, 1, a1k1, b1k1);
    MF(2, 0, a2k1, b0k1); MF(2, 1, a2k1, b1k1);
    MF(3, 0, a3k1, b0k1); MF(3, 1, a3k1, b1k1);
    __builtin_amdgcn_s_setprio(0);

    BAR();  // single barrier/phase: all waves' reads done (LGKM0 above), vmcnt drained
  }

  // ---- epilogue: 32x32 C/D layout: col = lane&31, row = (reg&3) + 8*(reg>>2) + 4*(lane>>5) ----
  const int ccol = lane & 31;
  const int r0 = (lane >> 5) << 2;
#pragma unroll
  for (int i = 0; i < 4; ++i) {
#pragma unroll
    for (int j = 0; j < 2; ++j) {
      size_t base = (size_t)(m0 + wm * 128 + i * 32 + r0) * NDIM + (n0 + wn * 64 + j * 32 + ccol);
#pragma unroll
      for (int reg = 0; reg < 16; ++reg) {
        int row = (reg & 3) + ((reg >> 2) << 3);
        out[base + (size_t)row * NDIM] = acc[i][j][reg];
      }
    }
  }
}

extern "C" void kernel_launch(void* const* d_in, const int* in_sizes, int n_in,
                              void* d_out, int out_size, void* d_ws, size_t ws_size,
                              hipStream_t stream) {
  const float* x = (const float*)d_in[0];
  const float* g1 = (const float*)d_in[1];
  const float* g2 = (const float*)d_in[2];
  float* out = (float*)d_out;

  unsigned short* Wt = (unsigned short*)d_ws;
  unsigned short* Xb = (unsigned short*)d_ws + (size_t)KDIM * NDIM;

  prep_kernel<<<16384 + NDIM, 256, 0, stream>>>(x, g1, g2, Xb, Wt);
  gemm_kernel<<<(TOKENS / 256) * (NDIM / 256), 512, 0, stream>>>(Xb, Wt, out);
}

// Round 6
// 291.927 us; speedup vs baseline: 1.1563x; 1.0626x over previous
//
#include <hip/hip_runtime.h>
#include <hip/hip_bf16.h>

// TT-linear: out(8192x4096) = x @ W, W from TT cores g1,g2.
// (1) prep: cvt x->bf16 + build W^T bf16. (2) GEMM: 256x256 tile, BK=64,
//     double-buffered LDS (128KB), 4 phases/K-tile, 16x16x32 MFMA,
//     128B-contiguous staging lines (8 rows x 128B per wave-instr), front-loaded
//     prefetch, one vmcnt(0) per tile after ph4 MFMA.
// R5->R6: theory = L2->CU transaction rate (~3-5 cyc per line) limited all prior
// rounds; 64B-granule staging wasted half of it. Also reverted to R2's verified
// 0-conflict read swizzle (c' = c ^ (row&7), 16x16 fragments).

#define TOKENS 8192
#define KDIM 4096
#define NDIM 4096

typedef __attribute__((ext_vector_type(8))) __bf16 bf16x8;
typedef __attribute__((ext_vector_type(4))) float f32x4;
typedef __attribute__((ext_vector_type(8))) unsigned short u16x8;

typedef __attribute__((address_space(1))) unsigned int as1_uint;
typedef __attribute__((address_space(3))) unsigned int as3_uint;

#define GLOAD_LDS16(gp, lp) \
  __builtin_amdgcn_global_load_lds((as1_uint*)(void*)(gp), (as3_uint*)(void*)(lp), 16, 0, 0)

#define BAR() asm volatile("s_barrier" ::: "memory")
#define LGKM0() asm volatile("s_waitcnt lgkmcnt(0)" ::: "memory")
#define VMCNT0() asm volatile("s_waitcnt vmcnt(0)" ::: "memory")

__device__ inline unsigned short f2bf(float f) {
  __hip_bfloat16 h = __float2bfloat16(f);
  return __builtin_bit_cast(unsigned short, h);
}

// ---------------- Kernel 1: merged prep (cvt x -> bf16 ; build Wt[n][k] bf16) ----------------
__global__ __launch_bounds__(256) void prep_kernel(const float* __restrict__ x,
                                                   const float* __restrict__ g1,
                                                   const float* __restrict__ g2,
                                                   unsigned short* __restrict__ xb,
                                                   unsigned short* __restrict__ wt) {
  __shared__ float a_s[64 * 16];  // [m1][r] for fixed n1
  __shared__ float b_s[16 * 64];  // [r][m2] for fixed n2
  const int bid = blockIdx.x;
  const int t = threadIdx.x;

  if (bid < 16384) {
    size_t i = (size_t)bid * 256 + t;
    const float4* p = reinterpret_cast<const float4*>(x) + i * 2;
    float4 v0 = p[0];
    float4 v1 = p[1];
    u16x8 u;
    u[0] = f2bf(v0.x); u[1] = f2bf(v0.y); u[2] = f2bf(v0.z); u[3] = f2bf(v0.w);
    u[4] = f2bf(v1.x); u[5] = f2bf(v1.y); u[6] = f2bf(v1.z); u[7] = f2bf(v1.w);
    reinterpret_cast<u16x8*>(xb)[i] = u;
    return;
  }

  const int n = bid - 16384;
  const int n1 = n >> 6, n2 = n & 63;
  for (int e = t; e < 1024; e += 256) {
    int m1 = e >> 4, r = e & 15;
    a_s[e] = g1[m1 * 1024 + n1 * 16 + r];
  }
  for (int e = t; e < 1024; e += 256) {
    int r = e >> 6, m2 = e & 63;
    b_s[e] = g2[r * 4096 + m2 * 64 + n2];
  }
  __syncthreads();

  unsigned short loc[16];
  const int kbase = t * 16;
#pragma unroll
  for (int kk = 0; kk < 16; ++kk) {
    int k = kbase + kk;
    int m1 = k >> 6, m2 = k & 63;
    float acc = 0.f;
#pragma unroll
    for (int r = 0; r < 16; ++r) acc += a_s[m1 * 16 + r] * b_s[r * 64 + m2];
    loc[kk] = f2bf(acc);
  }
  u16x8* dst = reinterpret_cast<u16x8*>(wt + (size_t)n * KDIM + kbase);
  dst[0] = *reinterpret_cast<u16x8*>(&loc[0]);
  dst[1] = *reinterpret_cast<u16x8*>(&loc[8]);
}

// ---------------- Kernel 2: GEMM 256x256, BK=64, dbuf, 4 phases/tile, 16x16x32 ----------------
// out[m][n] = sum_k Xb[m][k] * Wt[n][k].
// LDS buf b (0,1) at b*65536: A [256 rows][64 k] bf16 at +0 (32KB), B at +32768.
// Row = 128B = 8 chunks of 16B; swizzle chunk' = chunk ^ (row&7)  [R2-verified: 0 conflicts].
// Staging: thread t -> row t>>3, lds chunk t&7, inverse-swizzled src chunk (t&7)^((t>>3)&7);
//          one source-GLOAD covers 64 rows; per wave-instr = 8 rows x 128B contiguous.
// Schedule per tile s (buf s&1), stage tile s+1 (buf ^1):
//   ph1: read A i0-3 kk0 + B j0-3 kk0 ; stage B(s+1) g0-3 ; BAR; LGKM0; 16 MFMA; BAR
//   ph2: read A i4-7 kk0             ; stage A(s+1) g0-3 ; BAR; LGKM0; 16 MFMA; BAR
//   ph3: read A i0-3 kk1 + B kk1     ;                     BAR; LGKM0; 16 MFMA; BAR
//   ph4: read A i4-7 kk1             ; BAR; LGKM0; 16 MFMA; VMCNT0; BAR
// vmcnt(0) once per tile, after ph4's MFMA (stages have >= 1.5-phase lead).
__global__ __launch_bounds__(512, 2) void gemm_kernel(const unsigned short* __restrict__ Xb,
                                                      const unsigned short* __restrict__ Wt,
                                                      float* __restrict__ out) {
  __shared__ __align__(16) char lds[131072];

  const int t = threadIdx.x;
  const int lane = t & 63;
  const int wave = t >> 6;   // 0..7
  const int wm = wave >> 2;  // 0..1 : 128 output rows
  const int wn = wave & 3;   // 0..3 : 64 output cols

  // 8x8-per-XCD chunking: XCD (bid&7) owns an 8bm x 8bn region of the 32x16 grid
  const int bid = blockIdx.x;
  const int xcd = bid & 7, jj = bid >> 3;
  const int bm = ((xcd >> 1) << 3) + (jj >> 3);
  const int bn = ((xcd & 1) << 3) + (jj & 7);
  const int m0 = bm << 8, n0 = bn << 8;

  // staging geometry
  const int srow = t >> 3;                      // 0..63 rows per source-GLOAD
  const int csrc = (t & 7) ^ ((t >> 3) & 7);    // inverse-swizzled source chunk
  const unsigned short* aS = Xb + (size_t)(m0 + srow) * KDIM + csrc * 8;
  const unsigned short* bS = Wt + (size_t)(n0 + srow) * KDIM + csrc * 8;
  const int ldsW = wave << 10;  // wave-uniform 1KB slot

#define STG_A(kt, sb, g) \
  GLOAD_LDS16(aS + (size_t)(g) * 64 * KDIM + (size_t)(kt) * 64, lds + (sb) + (g) * 8192 + ldsW)
#define STG_B(kt, sb, g) \
  GLOAD_LDS16(bS + (size_t)(g) * 64 * KDIM + (size_t)(kt) * 64, lds + (sb) + 32768 + (g) * 8192 + ldsW)

  // fragment reads: row = base16 + (lane&15), global chunk = kk*4 + (lane>>4),
  // lds chunk = chunk ^ (row&7) = chunk ^ (lane&7); kk toggles chunk bit2 -> byte XOR 64.
  const int cO = ((lane >> 4) ^ (lane & 7)) << 4;
  const int aRowB = (wm * 128 + (lane & 15)) * 128;          // + i*2048 (+rb)
  const int bRowB = 32768 + (wn * 64 + (lane & 15)) * 128;   // + j*2048 (+rb)

#define RA(i, kk) (*(const bf16x8*)(lds + rb + aRowB + (i) * 2048 + (cO ^ ((kk) * 64))))
#define RB(j, kk) (*(const bf16x8*)(lds + rb + bRowB + (j) * 2048 + (cO ^ ((kk) * 64))))
#define MF(i, j, A, B) acc[i][j] = __builtin_amdgcn_mfma_f32_16x16x32_bf16((A), (B), acc[i][j], 0, 0, 0)

  f32x4 acc[8][4];
#pragma unroll
  for (int i = 0; i < 8; ++i)
#pragma unroll
    for (int j = 0; j < 4; ++j) acc[i][j] = (f32x4){0.f, 0.f, 0.f, 0.f};

  // ---- prologue: stage tile 0 into buf0, drain ----
  STG_A(0, 0, 0); STG_A(0, 0, 1); STG_A(0, 0, 2); STG_A(0, 0, 3);
  STG_B(0, 0, 0); STG_B(0, 0, 1); STG_B(0, 0, 2); STG_B(0, 0, 3);
  VMCNT0();
  BAR();

#pragma unroll 1
  for (int s = 0; s < 64; ++s) {
    const int rb = (s & 1) << 16;
    const int sb = rb ^ 65536;
    const int tn = (s + 1) & 63;  // s=63 wraps: dummy re-stage of tile 0, never read

    // ---- ph1: A i0-3 kk0 + B kk0 ; stage B(s+1) ----
    bf16x8 pa0 = RA(0, 0), pa1 = RA(1, 0), pa2 = RA(2, 0), pa3 = RA(3, 0);
    bf16x8 pb0 = RB(0, 0), pb1 = RB(1, 0), pb2 = RB(2, 0), pb3 = RB(3, 0);
    STG_B(tn, sb, 0); STG_B(tn, sb, 1); STG_B(tn, sb, 2); STG_B(tn, sb, 3);
    BAR(); LGKM0();
    __builtin_amdgcn_s_setprio(1);
    MF(0, 0, pa0, pb0); MF(0, 1, pa0, pb1); MF(0, 2, pa0, pb2); MF(0, 3, pa0, pb3);
    MF(1, 0, pa1, pb0); MF(1, 1, pa1, pb1); MF(1, 2, pa1, pb2); MF(1, 3, pa1, pb3);
    MF(2, 0, pa2, pb0); MF(2, 1, pa2, pb1); MF(2, 2, pa2, pb2); MF(2, 3, pa2, pb3);
    MF(3, 0, pa3, pb0); MF(3, 1, pa3, pb1); MF(3, 2, pa3, pb2); MF(3, 3, pa3, pb3);
    __builtin_amdgcn_s_setprio(0);
    BAR();

    // ---- ph2: A i4-7 kk0 ; stage A(s+1) ----
    bf16x8 pa4 = RA(4, 0), pa5 = RA(5, 0), pa6 = RA(6, 0), pa7 = RA(7, 0);
    STG_A(tn, sb, 0); STG_A(tn, sb, 1); STG_A(tn, sb, 2); STG_A(tn, sb, 3);
    BAR(); LGKM0();
    __builtin_amdgcn_s_setprio(1);
    MF(4, 0, pa4, pb0); MF(4, 1, pa4, pb1); MF(4, 2, pa4, pb2); MF(4, 3, pa4, pb3);
    MF(5, 0, pa5, pb0); MF(5, 1, pa5, pb1); MF(5, 2, pa5, pb2); MF(5, 3, pa5, pb3);
    MF(6, 0, pa6, pb0); MF(6, 1, pa6, pb1); MF(6, 2, pa6, pb2); MF(6, 3, pa6, pb3);
    MF(7, 0, pa7, pb0); MF(7, 1, pa7, pb1); MF(7, 2, pa7, pb2); MF(7, 3, pa7, pb3);
    __builtin_amdgcn_s_setprio(0);
    BAR();

    // ---- ph3: A i0-3 kk1 + B kk1 ----
    bf16x8 qa0 = RA(0, 1), qa1 = RA(1, 1), qa2 = RA(2, 1), qa3 = RA(3, 1);
    bf16x8 qb0 = RB(0, 1), qb1 = RB(1, 1), qb2 = RB(2, 1), qb3 = RB(3, 1);
    BAR(); LGKM0();
    __builtin_amdgcn_s_setprio(1);
    MF(0, 0, qa0, qb0); MF(0, 1, qa0, qb1); MF(0, 2, qa0, qb2); MF(0, 3, qa0, qb3);
    MF(1, 0, qa1, qb0); MF(1, 1, qa1, qb1); MF(1, 2, qa1, qb2); MF(1, 3, qa1, qb3);
    MF(2, 0, qa2, qb0); MF(2, 1, qa2, qb1); MF(2, 2, qa2, qb2); MF(2, 3, qa2, qb3);
    MF(3, 0, qa3, qb0); MF(3, 1, qa3, qb1); MF(3, 2, qa3, qb2); MF(3, 3, qa3, qb3);
    __builtin_amdgcn_s_setprio(0);
    BAR();

    // ---- ph4: A i4-7 kk1 ; MFMA ; drain stages (covered by MFMA) ----
    bf16x8 qa4 = RA(4, 1), qa5 = RA(5, 1), qa6 = RA(6, 1), qa7 = RA(7, 1);
    BAR(); LGKM0();
    __builtin_amdgcn_s_setprio(1);
    MF(4, 0, qa4, qb0); MF(4, 1, qa4, qb1); MF(4, 2, qa4, qb2); MF(4, 3, qa4, qb3);
    MF(5, 0, qa5, qb0); MF(5, 1, qa5, qb1); MF(5, 2, qa5, qb2); MF(5, 3, qa5, qb3);
    MF(6, 0, qa6, qb0); MF(6, 1, qa6, qb1); MF(6, 2, qa6, qb2); MF(6, 3, qa6, qb3);
    MF(7, 0, qa7, qb0); MF(7, 1, qa7, qb1); MF(7, 2, qa7, qb2); MF(7, 3, qa7, qb3);
    __builtin_amdgcn_s_setprio(0);
    VMCNT0();  // tile s+1 fully resident before next ph1's reads
    BAR();
  }

  // ---- epilogue: C/D layout col = lane&15, row = (lane>>4)*4 + q ----
  const int crow = (lane >> 4) << 2;
  const int ccol = lane & 15;
#pragma unroll
  for (int i = 0; i < 8; ++i) {
#pragma unroll
    for (int j = 0; j < 4; ++j) {
      size_t base = (size_t)(m0 + wm * 128 + i * 16 + crow) * NDIM + (n0 + wn * 64 + j * 16 + ccol);
#pragma unroll
      for (int q = 0; q < 4; ++q) out[base + (size_t)q * NDIM] = acc[i][j][q];
    }
  }
}

extern "C" void kernel_launch(void* const* d_in, const int* in_sizes, int n_in,
                              void* d_out, int out_size, void* d_ws, size_t ws_size,
                              hipStream_t stream) {
  const float* x = (const float*)d_in[0];
  const float* g1 = (const float*)d_in[1];
  const float* g2 = (const float*)d_in[2];
  float* out = (float*)d_out;

  unsigned short* Wt = (unsigned short*)d_ws;
  unsigned short* Xb = (unsigned short*)d_ws + (size_t)KDIM * NDIM;

  prep_kernel<<<16384 + NDIM, 256, 0, stream>>>(x, g1, g2, Xb, Wt);
  gemm_kernel<<<(TOKENS / 256) * (NDIM / 256), 512, 0, stream>>>(Xb, Wt, out);
}

// Round 7
// 274.420 us; speedup vs baseline: 1.2300x; 1.0638x over previous
//
#include <hip/hip_runtime.h>
#include <hip/hip_bf16.h>

// TT-linear: out(8192x4096) = x @ W, W from TT cores g1,g2.
// (1) prep: cvt x->bf16 + build W^T bf16. (2) GEMM: m201-style 8-phase template:
//     256x256 tile, BK=64, 2dbuf (even tiles buf0, odd buf1), per-phase 1 half-tile
//     stage (2 gloads), reads taper {12,8,4,0} per K-tile (C-quadrant phases),
//     counted vmcnt(4) at phases 4/8 only, setprio around MFMA, 16x16x32 MFMA,
//     chunk^(row&7) swizzle (0-conflict verified R6).

#define TOKENS 8192
#define KDIM 4096
#define NDIM 4096

typedef __attribute__((ext_vector_type(8))) __bf16 bf16x8;
typedef __attribute__((ext_vector_type(4))) float f32x4;
typedef __attribute__((ext_vector_type(8))) unsigned short u16x8;

typedef __attribute__((address_space(1))) unsigned int as1_uint;
typedef __attribute__((address_space(3))) unsigned int as3_uint;

#define GLOAD_LDS16(gp, lp) \
  __builtin_amdgcn_global_load_lds((as1_uint*)(void*)(gp), (as3_uint*)(void*)(lp), 16, 0, 0)

#define BAR() asm volatile("s_barrier" ::: "memory")
#define LGKM0() asm volatile("s_waitcnt lgkmcnt(0)" ::: "memory")
#define LGKM8() asm volatile("s_waitcnt lgkmcnt(8)" ::: "memory")
#define VMCNT4() asm volatile("s_waitcnt vmcnt(4)" ::: "memory")

__device__ inline unsigned short f2bf(float f) {
  __hip_bfloat16 h = __float2bfloat16(f);
  return __builtin_bit_cast(unsigned short, h);
}

// ---------------- Kernel 1: merged prep (cvt x -> bf16 ; build Wt[n][k] bf16) ----------------
__global__ __launch_bounds__(256) void prep_kernel(const float* __restrict__ x,
                                                   const float* __restrict__ g1,
                                                   const float* __restrict__ g2,
                                                   unsigned short* __restrict__ xb,
                                                   unsigned short* __restrict__ wt) {
  __shared__ float a_s[64 * 16];  // [m1][r] for fixed n1
  __shared__ float b_s[16 * 64];  // [r][m2] for fixed n2
  const int bid = blockIdx.x;
  const int t = threadIdx.x;

  if (bid < 16384) {
    size_t i = (size_t)bid * 256 + t;
    const float4* p = reinterpret_cast<const float4*>(x) + i * 2;
    float4 v0 = p[0];
    float4 v1 = p[1];
    u16x8 u;
    u[0] = f2bf(v0.x); u[1] = f2bf(v0.y); u[2] = f2bf(v0.z); u[3] = f2bf(v0.w);
    u[4] = f2bf(v1.x); u[5] = f2bf(v1.y); u[6] = f2bf(v1.z); u[7] = f2bf(v1.w);
    reinterpret_cast<u16x8*>(xb)[i] = u;
    return;
  }

  const int n = bid - 16384;
  const int n1 = n >> 6, n2 = n & 63;
  for (int e = t; e < 1024; e += 256) {
    int m1 = e >> 4, r = e & 15;
    a_s[e] = g1[m1 * 1024 + n1 * 16 + r];
  }
  for (int e = t; e < 1024; e += 256) {
    int r = e >> 6, m2 = e & 63;
    b_s[e] = g2[r * 4096 + m2 * 64 + n2];
  }
  __syncthreads();

  unsigned short loc[16];
  const int kbase = t * 16;
#pragma unroll
  for (int kk = 0; kk < 16; ++kk) {
    int k = kbase + kk;
    int m1 = k >> 6, m2 = k & 63;
    float acc = 0.f;
#pragma unroll
    for (int r = 0; r < 16; ++r) acc += a_s[m1 * 16 + r] * b_s[r * 64 + m2];
    loc[kk] = f2bf(acc);
  }
  u16x8* dst = reinterpret_cast<u16x8*>(wt + (size_t)n * KDIM + kbase);
  dst[0] = *reinterpret_cast<u16x8*>(&loc[0]);
  dst[1] = *reinterpret_cast<u16x8*>(&loc[8]);
}

// ---------------- Kernel 2: GEMM 256x256, BK=64, 8-phase/2-K-tile template ----------------
// out[m][n] = sum_k Xb[m][k] * Wt[n][k].
// LDS: buf0 @0 (even K-tiles), buf1 @65536 (odd): A[256][64]bf16 @+0, B @+32768.
// Row = 128B = 8 chunks; swizzle chunk' = chunk ^ (row&7) [R6-verified: 0 conflicts].
// Per K-tile (4 phases, C-quadrants, reads front-loaded to free A by ph2):
//   ph1: rd a0-3 kk01 (8) + b0-1 kk01 (4); stage; BAR; lgkm0; MFMA (i0-3)x(j0-1)
//   ph2: rd a4-7 kk01 (8);                 stage; BAR; lgkm0; MFMA (i4-7)x(j0-1)
//   ph3: rd b2-3 kk01 (4);                 stage; BAR; lgkm0; MFMA (i0-3)x(j2-3)
//   ph4:                                   stage; [vmcnt(4)]; BAR; MFMA (i4-7)x(j2-3)
// Stage slots (1 half-tile = 2 gloads each), iter u = tiles (2u, 2u+1):
//   ph1: B-h0(2u+1)  ph2: B-h1(2u+1)  ph3: A-h0(2u+2)  ph4: A-h1(2u+2) +vmcnt(4)
//   ph5: B-h0(2u+2)  ph6: B-h1(2u+2)  ph7: A-h0(2u+3)  ph8: A-h1(2u+3) +vmcnt(4)
// Ledger: at ph4, outstanding = {A0,A1,B0,B1(2u+1), A0,A1(2u+2)} = 6 groups;
// vmcnt(4) drains the 4 oldest groups = tile 2u+1 fully resident (4th-oldest is
// >=2 phases old -> no stall). WAR: every stage lands >=1 barrier after the last
// read of its region (A-reads complete by ph2, B-regions have >=3-phase margin).
__global__ __launch_bounds__(512, 2) void gemm_kernel(const unsigned short* __restrict__ Xb,
                                                      const unsigned short* __restrict__ Wt,
                                                      float* __restrict__ out) {
  __shared__ __align__(16) char lds[131072];

  const int t = threadIdx.x;
  const int lane = t & 63;
  const int wave = t >> 6;   // 0..7
  const int wm = wave >> 2;  // 0..1 : 128 output rows
  const int wn = wave & 3;   // 0..3 : 64 output cols

  // 8x8-per-XCD chunking
  const int bid = blockIdx.x;
  const int xcd = bid & 7, jj = bid >> 3;
  const int bm = ((xcd >> 1) << 3) + (jj >> 3);
  const int bn = ((xcd & 1) << 3) + (jj & 7);
  const int m0 = bm << 8, n0 = bn << 8;

  // staging geometry: thread t -> row t>>3 (0..63), lds chunk t&7,
  // inverse-swizzled source chunk (t&7)^((t>>3)&7).
  const int srow = t >> 3;
  const int csrc = (t & 7) ^ ((t >> 3) & 7);
  const unsigned short* aS = Xb + (size_t)(m0 + srow) * KDIM + csrc * 8;
  const unsigned short* bS = Wt + (size_t)(n0 + srow) * KDIM + csrc * 8;
  const int ldsW = wave << 10;  // wave-uniform 1KB slot

  // one half-tile (128 rows) = 2 gloads (64 rows x 128B each)
#define STGH_A(kt, bb, h) do { \
    const unsigned short* _s = aS + (size_t)((h) * 128) * KDIM + (size_t)(kt) * 64; \
    GLOAD_LDS16(_s, lds + (bb) + (h) * 16384 + ldsW); \
    GLOAD_LDS16(_s + (size_t)64 * KDIM, lds + (bb) + (h) * 16384 + 8192 + ldsW); \
  } while (0)
#define STGH_B(kt, bb, h) do { \
    const unsigned short* _s = bS + (size_t)((h) * 128) * KDIM + (size_t)(kt) * 64; \
    GLOAD_LDS16(_s, lds + (bb) + 32768 + (h) * 16384 + ldsW); \
    GLOAD_LDS16(_s + (size_t)64 * KDIM, lds + (bb) + 32768 + (h) * 16384 + 8192 + ldsW); \
  } while (0)

  // fragment reads: row = base16 + (lane&15), global chunk = kk*4 + (lane>>4),
  // lds chunk = chunk ^ (row&7) = chunk ^ (lane&7); kk toggles chunk bit2 -> byte XOR 64.
  const int cO = ((lane >> 4) ^ (lane & 7)) << 4;
  const int aRowB = (wm * 128 + (lane & 15)) * 128;
  const int bRowB = 32768 + (wn * 64 + (lane & 15)) * 128;

#define RA(i, kk, rb) (*(const bf16x8*)(lds + (rb) + aRowB + (i) * 2048 + (cO ^ ((kk) * 64))))
#define RB(j, kk, rb) (*(const bf16x8*)(lds + (rb) + bRowB + (j) * 2048 + (cO ^ ((kk) * 64))))
#define MF(i, j, A, B) acc[i][j] = __builtin_amdgcn_mfma_f32_16x16x32_bf16((A), (B), acc[i][j], 0, 0, 0)

  f32x4 acc[8][4];
#pragma unroll
  for (int i = 0; i < 8; ++i)
#pragma unroll
    for (int j = 0; j < 4; ++j) acc[i][j] = (f32x4){0.f, 0.f, 0.f, 0.f};

  // 4-phase body for one K-tile read from base RB_; S1..S4 are stage statements.
#define KTILE(RB_, S1, S2, S3, S4, W4) do { \
    /* ph1: a0-3 + b0-1 */ \
    bf16x8 a0k0 = RA(0, 0, RB_), a1k0 = RA(1, 0, RB_), a2k0 = RA(2, 0, RB_), a3k0 = RA(3, 0, RB_); \
    bf16x8 a0k1 = RA(0, 1, RB_), a1k1 = RA(1, 1, RB_), a2k1 = RA(2, 1, RB_), a3k1 = RA(3, 1, RB_); \
    bf16x8 b0k0 = RB(0, 0, RB_), b1k0 = RB(1, 0, RB_); \
    bf16x8 b0k1 = RB(0, 1, RB_), b1k1 = RB(1, 1, RB_); \
    S1; LGKM8(); BAR(); LGKM0(); \
    __builtin_amdgcn_s_setprio(1); \
    MF(0, 0, a0k0, b0k0); MF(0, 0, a0k1, b0k1); MF(0, 1, a0k0, b1k0); MF(0, 1, a0k1, b1k1); \
    MF(1, 0, a1k0, b0k0); MF(1, 0, a1k1, b0k1); MF(1, 1, a1k0, b1k0); MF(1, 1, a1k1, b1k1); \
    MF(2, 0, a2k0, b0k0); MF(2, 0, a2k1, b0k1); MF(2, 1, a2k0, b1k0); MF(2, 1, a2k1, b1k1); \
    MF(3, 0, a3k0, b0k0); MF(3, 0, a3k1, b0k1); MF(3, 1, a3k0, b1k0); MF(3, 1, a3k1, b1k1); \
    __builtin_amdgcn_s_setprio(0); BAR(); \
    /* ph2: a4-7 */ \
    bf16x8 a4k0 = RA(4, 0, RB_), a5k0 = RA(5, 0, RB_), a6k0 = RA(6, 0, RB_), a7k0 = RA(7, 0, RB_); \
    bf16x8 a4k1 = RA(4, 1, RB_), a5k1 = RA(5, 1, RB_), a6k1 = RA(6, 1, RB_), a7k1 = RA(7, 1, RB_); \
    S2; BAR(); LGKM0(); \
    __builtin_amdgcn_s_setprio(1); \
    MF(4, 0, a4k0, b0k0); MF(4, 0, a4k1, b0k1); MF(4, 1, a4k0, b1k0); MF(4, 1, a4k1, b1k1); \
    MF(5, 0, a5k0, b0k0); MF(5, 0, a5k1, b0k1); MF(5, 1, a5k0, b1k0); MF(5, 1, a5k1, b1k1); \
    MF(6, 0, a6k0, b0k0); MF(6, 0, a6k1, b0k1); MF(6, 1, a6k0, b1k0); MF(6, 1, a6k1, b1k1); \
    MF(7, 0, a7k0, b0k0); MF(7, 0, a7k1, b0k1); MF(7, 1, a7k0, b1k0); MF(7, 1, a7k1, b1k1); \
    __builtin_amdgcn_s_setprio(0); BAR(); \
    /* ph3: b2-3 */ \
    bf16x8 b2k0 = RB(2, 0, RB_), b3k0 = RB(3, 0, RB_); \
    bf16x8 b2k1 = RB(2, 1, RB_), b3k1 = RB(3, 1, RB_); \
    S3; BAR(); LGKM0(); \
    __builtin_amdgcn_s_setprio(1); \
    MF(0, 2, a0k0, b2k0); MF(0, 2, a0k1, b2k1); MF(0, 3, a0k0, b3k0); MF(0, 3, a0k1, b3k1); \
    MF(1, 2, a1k0, b2k0); MF(1, 2, a1k1, b2k1); MF(1, 3, a1k0, b3k0); MF(1, 3, a1k1, b3k1); \
    MF(2, 2, a2k0, b2k0); MF(2, 2, a2k1, b2k1); MF(2, 3, a2k0, b3k0); MF(2, 3, a2k1, b3k1); \
    MF(3, 2, a3k0, b2k0); MF(3, 2, a3k1, b2k1); MF(3, 3, a3k0, b3k0); MF(3, 3, a3k1, b3k1); \
    __builtin_amdgcn_s_setprio(0); BAR(); \
    /* ph4: no reads */ \
    S4; W4; BAR(); \
    __builtin_amdgcn_s_setprio(1); \
    MF(4, 2, a4k0, b2k0); MF(4, 2, a4k1, b2k1); MF(4, 3, a4k0, b3k0); MF(4, 3, a4k1, b3k1); \
    MF(5, 2, a5k0, b2k0); MF(5, 2, a5k1, b2k1); MF(5, 3, a5k0, b3k0); MF(5, 3, a5k1, b3k1); \
    MF(6, 2, a6k0, b2k0); MF(6, 2, a6k1, b2k1); MF(6, 3, a6k0, b3k0); MF(6, 3, a6k1, b3k1); \
    MF(7, 2, a7k0, b2k0); MF(7, 2, a7k1, b2k1); MF(7, 3, a7k0, b3k0); MF(7, 3, a7k1, b3k1); \
    __builtin_amdgcn_s_setprio(0); BAR(); \
  } while (0)

  // ---- prologue: t0 (4 half-tiles) -> buf0, t1's A halves -> buf1; vmcnt(4) -> t0 resident ----
  STGH_A(0, 0, 0); STGH_A(0, 0, 1); STGH_B(0, 0, 0); STGH_B(0, 0, 1);
  STGH_A(1, 65536, 0); STGH_A(1, 65536, 1);
  VMCNT4();
  BAR();

#pragma unroll 1
  for (int u = 0; u < 32; ++u) {
    const int t1 = 2 * u + 1;
    const int t2n = (2 * u + 2) & 63;  // wraps at u=31 -> dummy re-stage, never read
    const int t3n = (2 * u + 3) & 63;

    // K-tile 2u (buf0); stages: B-h0(t1), B-h1(t1), A-h0(t2), A-h1(t2)+vmcnt(4)
    KTILE(0,
          STGH_B(t1, 65536, 0),
          STGH_B(t1, 65536, 1),
          STGH_A(t2n, 0, 0),
          STGH_A(t2n, 0, 1),
          VMCNT4());

    // K-tile 2u+1 (buf1); stages: B-h0(t2), B-h1(t2), A-h0(t3), A-h1(t3)+vmcnt(4)
    KTILE(65536,
          STGH_B(t2n, 0, 0),
          STGH_B(t2n, 0, 1),
          STGH_A(t3n, 65536, 0),
          STGH_A(t3n, 65536, 1),
          VMCNT4());
  }

  // ---- epilogue: C/D layout col = lane&15, row = (lane>>4)*4 + q ----
  const int crow = (lane >> 4) << 2;
  const int ccol = lane & 15;
#pragma unroll
  for (int i = 0; i < 8; ++i) {
#pragma unroll
    for (int j = 0; j < 4; ++j) {
      size_t base = (size_t)(m0 + wm * 128 + i * 16 + crow) * NDIM + (n0 + wn * 64 + j * 16 + ccol);
#pragma unroll
      for (int q = 0; q < 4; ++q) out[base + (size_t)q * NDIM] = acc[i][j][q];
    }
  }
}

extern "C" void kernel_launch(void* const* d_in, const int* in_sizes, int n_in,
                              void* d_out, int out_size, void* d_ws, size_t ws_size,
                              hipStream_t stream) {
  const float* x = (const float*)d_in[0];
  const float* g1 = (const float*)d_in[1];
  const float* g2 = (const float*)d_in[2];
  float* out = (float*)d_out;

  unsigned short* Wt = (unsigned short*)d_ws;
  unsigned short* Xb = (unsigned short*)d_ws + (size_t)KDIM * NDIM;

  prep_kernel<<<16384 + NDIM, 256, 0, stream>>>(x, g1, g2, Xb, Wt);
  gemm_kernel<<<(TOKENS / 256) * (NDIM / 256), 512, 0, stream>>>(Xb, Wt, out);
}